// Round 1
// baseline (398.912 us; speedup 1.0000x reference)
//
#include <hip/hip_runtime.h>

#define F0 128
#define F1 64
#define F2 32

// ---------------- degree / normalization ----------------
__global__ void deg_init(float* deg, int N) {
    int i = blockIdx.x * 256 + threadIdx.x;
    if (i < N) deg[i] = 1.0f;  // self-loop contributes 1 to in-degree
}

__global__ void deg_count(const int* __restrict__ col, float* deg, int E) {
    int e = blockIdx.x * 256 + threadIdx.x;
    if (e < E) atomicAdd(&deg[col[e]], 1.0f);
}

__global__ void deg_rsqrt(float* deg, int N) {
    int i = blockIdx.x * 256 + threadIdx.x;
    if (i < N) deg[i] = rsqrtf(deg[i]);  // deg >= 1 always
}

// ---------------- layer 1 GEMM: xw1 = x @ W1  (N x 128 @ 128 x 64) ----------------
// block = 256 threads = 4 rows x 64 cols; W1 (32KB) + 4 x-rows (2KB) staged in LDS
__global__ void gemm1(const float* __restrict__ x, const float* __restrict__ W,
                      float* __restrict__ xw, int N) {
    __shared__ float Wl[F0 * F1];
    __shared__ float Xl[4 * F0];
    for (int i = threadIdx.x; i < F0 * F1; i += 256) Wl[i] = W[i];
    int base = blockIdx.x * 4;
    for (int i = threadIdx.x; i < 4 * F0; i += 256) {
        int r = base + i / F0;
        Xl[i] = (r < N) ? x[(size_t)r * F0 + (i & (F0 - 1))] : 0.0f;
    }
    __syncthreads();
    int j = threadIdx.x & 63;
    int rl = threadIdx.x >> 6;
    int r = base + rl;
    if (r >= N) return;
    float s = 0.0f;
#pragma unroll 8
    for (int k = 0; k < F0; ++k) s = fmaf(Xl[rl * F0 + k], Wl[k * F1 + j], s);
    xw[(size_t)r * F1 + j] = s;
}

// ---------------- layer 2 GEMM (fused ReLU on load): h2w = relu(out1) @ W2 ----------------
// block = 256 threads = 8 rows x 32 cols
__global__ void gemm2(const float* __restrict__ h, const float* __restrict__ W,
                      float* __restrict__ hw, int N) {
    __shared__ float Wl[F1 * F2];  // 8KB
    __shared__ float Hl[8 * F1];   // 2KB
    for (int i = threadIdx.x; i < F1 * F2; i += 256) Wl[i] = W[i];
    int base = blockIdx.x * 8;
    for (int i = threadIdx.x; i < 8 * F1; i += 256) {
        int r = base + i / F1;
        Hl[i] = (r < N) ? fmaxf(h[(size_t)r * F1 + (i & (F1 - 1))], 0.0f) : 0.0f;
    }
    __syncthreads();
    int j = threadIdx.x & 31;
    int rl = threadIdx.x >> 5;
    int r = base + rl;
    if (r >= N) return;
    float s = 0.0f;
#pragma unroll 8
    for (int k = 0; k < F1; ++k) s = fmaf(Hl[rl * F1 + k], Wl[k * F2 + j], s);
    hw[(size_t)r * F2 + j] = s;
}

// ---------------- aggregation init: out = xw * dinv^2 + b (self-loop message + bias) ----------------
__global__ void init_agg1(const float* __restrict__ xw, const float* __restrict__ dinv,
                          const float* __restrict__ b, float* __restrict__ out, int N) {
    int t = blockIdx.x * 256 + threadIdx.x;
    int i = t >> 6, j = t & 63;
    if (i >= N) return;
    float d = dinv[i];
    out[t] = xw[t] * d * d + b[j];
}

__global__ void init_agg2(const float* __restrict__ hw, const float* __restrict__ dinv,
                          const float* __restrict__ b, float* __restrict__ out, int N) {
    int t = blockIdx.x * 256 + threadIdx.x;
    int i = t >> 5, j = t & 31;
    if (i >= N) return;
    float d = dinv[i];
    out[t] = hw[t] * d * d + b[j];
}

// ---------------- edge scatter: out[col] += xw[row] * dinv[row]*dinv[col] ----------------
// layer1: one wave (64 lanes) per edge -> 256B coalesced gather + 256B coalesced atomics
__global__ void scatter1(const int* __restrict__ row, const int* __restrict__ col,
                         const float* __restrict__ dinv, const float* __restrict__ xw,
                         float* out, int E) {
    int t = blockIdx.x * 256 + threadIdx.x;
    int e = t >> 6, j = t & 63;
    if (e >= E) return;
    int r = row[e], c = col[e];
    float nrm = dinv[r] * dinv[c];
    atomicAdd(&out[(size_t)c * F1 + j], xw[(size_t)r * F1 + j] * nrm);
}

// layer2: 32 lanes per edge (2 edges per wave)
__global__ void scatter2(const int* __restrict__ row, const int* __restrict__ col,
                         const float* __restrict__ dinv, const float* __restrict__ hw,
                         float* out, int E) {
    int t = blockIdx.x * 256 + threadIdx.x;
    int e = t >> 5, j = t & 31;
    if (e >= E) return;
    int r = row[e], c = col[e];
    float nrm = dinv[r] * dinv[c];
    atomicAdd(&out[(size_t)c * F2 + j], hw[(size_t)r * F2 + j] * nrm);
}

// ---------------- log_softmax over rows of 32, in place ----------------
__global__ void logsm(float* __restrict__ out, int N) {
    int t = blockIdx.x * 256 + threadIdx.x;
    int r = t >> 5;
    if (r >= N) return;
    float v = out[t];
    float m = v;
    for (int off = 16; off; off >>= 1) m = fmaxf(m, __shfl_xor(m, off, 32));
    float ex = expf(v - m);
    float s = ex;
    for (int off = 16; off; off >>= 1) s += __shfl_xor(s, off, 32);
    out[t] = v - m - logf(s);
}

extern "C" void kernel_launch(void* const* d_in, const int* in_sizes, int n_in,
                              void* d_out, int out_size, void* d_ws, size_t ws_size,
                              hipStream_t stream) {
    const float* x  = (const float*)d_in[0];
    const int*   ei = (const int*)d_in[1];   // [2, E] int32 (JAX truncates int64 -> int32)
    const float* W1 = (const float*)d_in[2];
    const float* b1 = (const float*)d_in[3];
    const float* W2 = (const float*)d_in[4];
    const float* b2 = (const float*)d_in[5];

    int N = in_sizes[0] / F0;
    int E = in_sizes[1] / 2;
    const int* row = ei;
    const int* col = ei + E;

    // workspace layout (floats): dinv[N pad64] | xw1[N*64] | out1[N*64]
    // h2w reuses the xw1 region (xw1 dead after scatter1; gemm2 reads out1).
    float* ws   = (float*)d_ws;
    float* dinv = ws;
    float* xw1  = ws + (((size_t)N + 63) & ~(size_t)63);
    float* out1 = xw1 + (size_t)N * F1;
    float* h2w  = xw1;
    float* out2 = (float*)d_out;

    int nb;
    nb = (N + 255) / 256;
    deg_init<<<nb, 256, 0, stream>>>(dinv, N);
    nb = (E + 255) / 256;
    deg_count<<<nb, 256, 0, stream>>>(col, dinv, E);
    nb = (N + 255) / 256;
    deg_rsqrt<<<nb, 256, 0, stream>>>(dinv, N);

    gemm1<<<(N + 3) / 4, 256, 0, stream>>>(x, W1, xw1, N);

    nb = (int)(((size_t)N * F1 + 255) / 256);
    init_agg1<<<nb, 256, 0, stream>>>(xw1, dinv, b1, out1, N);
    nb = (int)(((size_t)E * F1 + 255) / 256);
    scatter1<<<nb, 256, 0, stream>>>(row, col, dinv, xw1, out1, E);

    gemm2<<<(N + 7) / 8, 256, 0, stream>>>(out1, W2, h2w, N);

    nb = (int)(((size_t)N * F2 + 255) / 256);
    init_agg2<<<nb, 256, 0, stream>>>(h2w, dinv, b2, out2, N);
    nb = (int)(((size_t)E * F2 + 255) / 256);
    scatter2<<<nb, 256, 0, stream>>>(row, col, dinv, h2w, out2, E);

    nb = (int)(((size_t)N * F2 + 255) / 256);
    logsm<<<nb, 256, 0, stream>>>(out2, N);
}

// Round 2
// 387.250 us; speedup vs baseline: 1.0301x; 1.0301x over previous
//
#include <hip/hip_runtime.h>

#define F0 128
#define F1 64
#define F2 32
#define SCAN_T 1024

// ================= CSR build =================
__global__ void zero_cnt(int* cnt, int N) {
    int i = blockIdx.x * 256 + threadIdx.x;
    if (i < N) cnt[i] = 0;
}

__global__ void count_deg(const int* __restrict__ col, int* cnt, int E) {
    int e = blockIdx.x * 256 + threadIdx.x;
    if (e < E) atomicAdd(&cnt[col[e]], 1);
}

// single-block hierarchical exclusive scan of cnt -> ptr; also dinv = rsqrt(cnt+1)
// and cur = ptr (cur may alias cnt: each element is read before written, same thread)
__global__ __launch_bounds__(SCAN_T) void scan_ptr(const int* __restrict__ cnt,
                                                   int* __restrict__ ptr,
                                                   int* __restrict__ cur,
                                                   float* __restrict__ dinv,
                                                   int N, int E) {
    __shared__ int sums[SCAN_T];
    int t = threadIdx.x;
    int chunk = (N + SCAN_T - 1) / SCAN_T;
    int base = t * chunk;
    int s = 0;
    for (int i = 0; i < chunk; ++i) {
        int idx = base + i;
        if (idx < N) s += cnt[idx];
    }
    sums[t] = s;
    __syncthreads();
    for (int off = 1; off < SCAN_T; off <<= 1) {   // Hillis-Steele inclusive scan
        int v = (t >= off) ? sums[t - off] : 0;
        __syncthreads();
        sums[t] += v;
        __syncthreads();
    }
    int run = sums[t] - s;  // exclusive prefix of this thread's chunk
    for (int i = 0; i < chunk; ++i) {
        int idx = base + i;
        if (idx < N) {
            int c = cnt[idx];          // read BEFORE cur write (allows cur==cnt alias)
            ptr[idx] = run;
            dinv[idx] = rsqrtf((float)(c + 1));   // +1 self-loop; deg>=1 always
            cur[idx] = run;
            run += c;
        }
    }
    if (t == SCAN_T - 1) ptr[N] = E;
}

// counting-sort fill: edges[pos] = (row, norm) bucketed by col
__global__ void edge_fill(const int* __restrict__ row, const int* __restrict__ col,
                          const float* __restrict__ dinv, int* cur,
                          uint2* __restrict__ edges, int E) {
    int e = blockIdx.x * 256 + threadIdx.x;
    if (e >= E) return;
    int r = row[e], c = col[e];
    float nrm = dinv[r] * dinv[c];
    int pos = atomicAdd(&cur[c], 1);
    edges[pos] = make_uint2((unsigned)r, __float_as_uint(nrm));
}

// ================= layer 1 GEMM: xw1 = x @ W1 (N x 128 @ 128 x 64) =================
__global__ void gemm1(const float* __restrict__ x, const float* __restrict__ W,
                      float* __restrict__ xw, int N) {
    __shared__ float Wl[F0 * F1];
    __shared__ float Xl[4 * F0];
    for (int i = threadIdx.x; i < F0 * F1; i += 256) Wl[i] = W[i];
    int base = blockIdx.x * 4;
    for (int i = threadIdx.x; i < 4 * F0; i += 256) {
        int r = base + i / F0;
        Xl[i] = (r < N) ? x[(size_t)r * F0 + (i & (F0 - 1))] : 0.0f;
    }
    __syncthreads();
    int j = threadIdx.x & 63;
    int rl = threadIdx.x >> 6;
    int r = base + rl;
    if (r >= N) return;
    float s = 0.0f;
#pragma unroll 8
    for (int k = 0; k < F0; ++k) s = fmaf(Xl[rl * F0 + k], Wl[k * F1 + j], s);
    xw[(size_t)r * F1 + j] = s;
}

// ================= layer 2 GEMM (ReLU fused on load): h2w = relu(out1) @ W2 =================
__global__ void gemm2(const float* __restrict__ h, const float* __restrict__ W,
                      float* __restrict__ hw, int N) {
    __shared__ float Wl[F1 * F2];
    __shared__ float Hl[8 * F1];
    for (int i = threadIdx.x; i < F1 * F2; i += 256) Wl[i] = W[i];
    int base = blockIdx.x * 8;
    for (int i = threadIdx.x; i < 8 * F1; i += 256) {
        int r = base + i / F1;
        Hl[i] = (r < N) ? fmaxf(h[(size_t)r * F1 + (i & (F1 - 1))], 0.0f) : 0.0f;
    }
    __syncthreads();
    int j = threadIdx.x & 31;
    int rl = threadIdx.x >> 5;
    int r = base + rl;
    if (r >= N) return;
    float s = 0.0f;
#pragma unroll 8
    for (int k = 0; k < F1; ++k) s = fmaf(Hl[rl * F1 + k], Wl[k * F2 + j], s);
    hw[(size_t)r * F2 + j] = s;
}

// ================= layer 1 aggregation (gather): one wave per node =================
// out[i,:] = b + dinv[i]^2 * xw[i,:] + sum_{e in col-bucket i} norm_e * xw[row_e,:]
__global__ void agg1(const int* __restrict__ ptr, const uint2* __restrict__ edges,
                     const float* __restrict__ xw, const float* __restrict__ dinv,
                     const float* __restrict__ b, float* __restrict__ out, int N) {
    int t = blockIdx.x * 256 + threadIdx.x;
    int i = t >> 6, j = t & 63;
    if (i >= N) return;
    float d = dinv[i];
    float acc = xw[(size_t)i * F1 + j] * d * d + b[j];
    int e = ptr[i], end = ptr[i + 1];
    // unroll x2: two independent broadcast loads + two independent gathers in flight
    for (; e + 1 < end; e += 2) {
        uint2 e0 = edges[e], e1 = edges[e + 1];
        float v0 = xw[(size_t)e0.x * F1 + j];
        float v1 = xw[(size_t)e1.x * F1 + j];
        acc += v0 * __uint_as_float(e0.y);
        acc += v1 * __uint_as_float(e1.y);
    }
    if (e < end) {
        uint2 e0 = edges[e];
        acc += xw[(size_t)e0.x * F1 + j] * __uint_as_float(e0.y);
    }
    out[(size_t)i * F1 + j] = acc;
}

// ================= layer 2 aggregation + fused log_softmax: half-wave per node =================
__global__ void agg2_lsm(const int* __restrict__ ptr, const uint2* __restrict__ edges,
                         const float* __restrict__ hw, const float* __restrict__ dinv,
                         const float* __restrict__ b, float* __restrict__ out, int N) {
    int t = blockIdx.x * 256 + threadIdx.x;
    int i = t >> 5, j = t & 31;
    if (i >= N) return;
    float d = dinv[i];
    float acc = hw[(size_t)i * F2 + j] * d * d + b[j];
    int e = ptr[i], end = ptr[i + 1];
    for (; e + 1 < end; e += 2) {
        uint2 e0 = edges[e], e1 = edges[e + 1];
        float v0 = hw[(size_t)e0.x * F2 + j];
        float v1 = hw[(size_t)e1.x * F2 + j];
        acc += v0 * __uint_as_float(e0.y);
        acc += v1 * __uint_as_float(e1.y);
    }
    if (e < end) {
        uint2 e0 = edges[e];
        acc += hw[(size_t)e0.x * F2 + j] * __uint_as_float(e0.y);
    }
    // fused log_softmax across the 32 lanes holding this row
    float m = acc;
    for (int off = 16; off; off >>= 1) m = fmaxf(m, __shfl_xor(m, off, 32));
    float s = expf(acc - m);
    for (int off = 16; off; off >>= 1) s += __shfl_xor(s, off, 32);
    out[(size_t)i * F2 + j] = acc - m - logf(s);
}

extern "C" void kernel_launch(void* const* d_in, const int* in_sizes, int n_in,
                              void* d_out, int out_size, void* d_ws, size_t ws_size,
                              hipStream_t stream) {
    const float* x  = (const float*)d_in[0];
    const int*   ei = (const int*)d_in[1];   // [2, E] int32
    const float* W1 = (const float*)d_in[2];
    const float* b1 = (const float*)d_in[3];
    const float* W2 = (const float*)d_in[4];
    const float* b2 = (const float*)d_in[5];

    int N = in_sizes[0] / F0;
    int E = in_sizes[1] / 2;
    const int* row = ei;
    const int* col = ei + E;

    // workspace layout (4B words), Np = N padded to 64 so every region is 256B-aligned
    size_t Np = ((size_t)N + 63) & ~(size_t)63;
    int*   cnt   = (int*)d_ws;              // Np   (reused as cur)
    int*   ptr   = cnt + Np;                // Np+64
    float* dinv  = (float*)(ptr + Np + 64); // Np
    uint2* edges = (uint2*)(dinv + Np);     // E * 2 words
    float* xw1   = (float*)(edges + E);     // N*64  (reused as h2w)
    float* out1  = xw1 + (size_t)N * F1;    // N*64
    int*   cur   = cnt;
    float* h2w   = xw1;
    float* out2  = (float*)d_out;

    int nbN = (N + 255) / 256;
    int nbE = (E + 255) / 256;

    zero_cnt<<<nbN, 256, 0, stream>>>(cnt, N);
    count_deg<<<nbE, 256, 0, stream>>>(col, cnt, E);
    scan_ptr<<<1, SCAN_T, 0, stream>>>(cnt, ptr, cur, dinv, N, E);
    edge_fill<<<nbE, 256, 0, stream>>>(row, col, dinv, cur, edges, E);

    gemm1<<<(N + 3) / 4, 256, 0, stream>>>(x, W1, xw1, N);
    agg1<<<(int)(((size_t)N * F1 + 255) / 256), 256, 0, stream>>>(ptr, edges, xw1, dinv, b1, out1, N);

    gemm2<<<(N + 7) / 8, 256, 0, stream>>>(out1, W2, h2w, N);
    agg2_lsm<<<(int)(((size_t)N * F2 + 255) / 256), 256, 0, stream>>>(ptr, edges, h2w, dinv, b2, out2, N);
}

// Round 3
// 248.619 us; speedup vs baseline: 1.6045x; 1.5576x over previous
//
#include <hip/hip_runtime.h>

#define F0 128
#define F1 64
#define F2 32

// ================= CSR build =================
__global__ void count_deg(const int* __restrict__ col, int* cnt, int E) {
    int e = blockIdx.x * 256 + threadIdx.x;
    if (e < E) atomicAdd(&cnt[col[e]], 1);
}

// phase A: per-block (256-elem segment) sums of cnt
__global__ void scan_partial(const int* __restrict__ cnt, int* __restrict__ partial, int N) {
    __shared__ int red[256];
    int i = blockIdx.x * 256 + threadIdx.x;
    red[threadIdx.x] = (i < N) ? cnt[i] : 0;
    __syncthreads();
    for (int off = 128; off; off >>= 1) {
        if (threadIdx.x < off) red[threadIdx.x] += red[threadIdx.x + off];
        __syncthreads();
    }
    if (threadIdx.x == 0) partial[blockIdx.x] = red[0];
}

// phase B: exclusive scan of the per-block totals (nb <= 1024), single block
__global__ __launch_bounds__(1024) void scan_block(int* partial, int nb) {
    __shared__ int s[1024];
    int t = threadIdx.x;
    int v = (t < nb) ? partial[t] : 0;
    s[t] = v;
    __syncthreads();
    for (int off = 1; off < 1024; off <<= 1) {   // Hillis-Steele inclusive
        int u = (t >= off) ? s[t - off] : 0;
        __syncthreads();
        s[t] += u;
        __syncthreads();
    }
    if (t < nb) partial[t] = s[t] - v;           // exclusive
}

// phase C: local 256-wide scan + block offset -> ptr/cur; dinv = rsqrt(deg+1)
// cur may alias cnt: each element read once (kernel start) before any write.
__global__ void scan_final(const int* __restrict__ cnt, const int* __restrict__ partial,
                           int* __restrict__ ptr, int* __restrict__ cur,
                           float* __restrict__ dinv, int N, int E) {
    __shared__ int s[256];
    int t = threadIdx.x;
    int i = blockIdx.x * 256 + t;
    int v = (i < N) ? cnt[i] : 0;
    s[t] = v;
    __syncthreads();
    for (int off = 1; off < 256; off <<= 1) {    // Hillis-Steele inclusive
        int u = (t >= off) ? s[t - off] : 0;
        __syncthreads();
        s[t] += u;
        __syncthreads();
    }
    if (i < N) {
        int p = partial[blockIdx.x] + s[t] - v;  // exclusive global prefix
        ptr[i] = p;
        cur[i] = p;
        dinv[i] = rsqrtf((float)(v + 1));        // +1 self-loop
    } else if (i == N) {
        ptr[N] = E;
    }
}

// counting-sort fill: edges[pos] = (row, norm) bucketed by col
__global__ void edge_fill(const int* __restrict__ row, const int* __restrict__ col,
                          const float* __restrict__ dinv, int* cur,
                          uint2* __restrict__ edges, int E) {
    int e = blockIdx.x * 256 + threadIdx.x;
    if (e >= E) return;
    int r = row[e], c = col[e];
    float nrm = dinv[r] * dinv[c];
    int pos = atomicAdd(&cur[c], 1);
    edges[pos] = make_uint2((unsigned)r, __float_as_uint(nrm));
}

// ================= layer 1 GEMM: xw1 = x @ W1 (N x 128 @ 128 x 64) =================
__global__ void gemm1(const float* __restrict__ x, const float* __restrict__ W,
                      float* __restrict__ xw, int N) {
    __shared__ float Wl[F0 * F1];
    __shared__ float Xl[4 * F0];
    for (int i = threadIdx.x; i < F0 * F1; i += 256) Wl[i] = W[i];
    int base = blockIdx.x * 4;
    for (int i = threadIdx.x; i < 4 * F0; i += 256) {
        int r = base + i / F0;
        Xl[i] = (r < N) ? x[(size_t)r * F0 + (i & (F0 - 1))] : 0.0f;
    }
    __syncthreads();
    int j = threadIdx.x & 63;
    int rl = threadIdx.x >> 6;
    int r = base + rl;
    if (r >= N) return;
    float s = 0.0f;
#pragma unroll 8
    for (int k = 0; k < F0; ++k) s = fmaf(Xl[rl * F0 + k], Wl[k * F1 + j], s);
    xw[(size_t)r * F1 + j] = s;
}

// ================= layer 2 GEMM (ReLU fused on load): h2w = relu(out1) @ W2 =================
__global__ void gemm2(const float* __restrict__ h, const float* __restrict__ W,
                      float* __restrict__ hw, int N) {
    __shared__ float Wl[F1 * F2];
    __shared__ float Hl[8 * F1];
    for (int i = threadIdx.x; i < F1 * F2; i += 256) Wl[i] = W[i];
    int base = blockIdx.x * 8;
    for (int i = threadIdx.x; i < 8 * F1; i += 256) {
        int r = base + i / F1;
        Hl[i] = (r < N) ? fmaxf(h[(size_t)r * F1 + (i & (F1 - 1))], 0.0f) : 0.0f;
    }
    __syncthreads();
    int j = threadIdx.x & 31;
    int rl = threadIdx.x >> 5;
    int r = base + rl;
    if (r >= N) return;
    float s = 0.0f;
#pragma unroll 8
    for (int k = 0; k < F1; ++k) s = fmaf(Hl[rl * F1 + k], Wl[k * F2 + j], s);
    hw[(size_t)r * F2 + j] = s;
}

// ================= layer 1 aggregation (gather): one wave per node =================
__global__ void agg1(const int* __restrict__ ptr, const uint2* __restrict__ edges,
                     const float* __restrict__ xw, const float* __restrict__ dinv,
                     const float* __restrict__ b, float* __restrict__ out, int N) {
    int t = blockIdx.x * 256 + threadIdx.x;
    int i = t >> 6, j = t & 63;
    if (i >= N) return;
    float d = dinv[i];
    float acc = xw[(size_t)i * F1 + j] * d * d + b[j];
    int e = ptr[i], end = ptr[i + 1];
    for (; e + 1 < end; e += 2) {
        uint2 e0 = edges[e], e1 = edges[e + 1];
        float v0 = xw[(size_t)e0.x * F1 + j];
        float v1 = xw[(size_t)e1.x * F1 + j];
        acc += v0 * __uint_as_float(e0.y);
        acc += v1 * __uint_as_float(e1.y);
    }
    if (e < end) {
        uint2 e0 = edges[e];
        acc += xw[(size_t)e0.x * F1 + j] * __uint_as_float(e0.y);
    }
    out[(size_t)i * F1 + j] = acc;
}

// ================= layer 2 aggregation + fused log_softmax: half-wave per node =================
__global__ void agg2_lsm(const int* __restrict__ ptr, const uint2* __restrict__ edges,
                         const float* __restrict__ hw, const float* __restrict__ dinv,
                         const float* __restrict__ b, float* __restrict__ out, int N) {
    int t = blockIdx.x * 256 + threadIdx.x;
    int i = t >> 5, j = t & 31;
    if (i >= N) return;
    float d = dinv[i];
    float acc = hw[(size_t)i * F2 + j] * d * d + b[j];
    int e = ptr[i], end = ptr[i + 1];
    for (; e + 1 < end; e += 2) {
        uint2 e0 = edges[e], e1 = edges[e + 1];
        float v0 = hw[(size_t)e0.x * F2 + j];
        float v1 = hw[(size_t)e1.x * F2 + j];
        acc += v0 * __uint_as_float(e0.y);
        acc += v1 * __uint_as_float(e1.y);
    }
    if (e < end) {
        uint2 e0 = edges[e];
        acc += hw[(size_t)e0.x * F2 + j] * __uint_as_float(e0.y);
    }
    float m = acc;
    for (int off = 16; off; off >>= 1) m = fmaxf(m, __shfl_xor(m, off, 32));
    float s = expf(acc - m);
    for (int off = 16; off; off >>= 1) s += __shfl_xor(s, off, 32);
    out[(size_t)i * F2 + j] = acc - m - logf(s);
}

extern "C" void kernel_launch(void* const* d_in, const int* in_sizes, int n_in,
                              void* d_out, int out_size, void* d_ws, size_t ws_size,
                              hipStream_t stream) {
    const float* x  = (const float*)d_in[0];
    const int*   ei = (const int*)d_in[1];   // [2, E] int32
    const float* W1 = (const float*)d_in[2];
    const float* b1 = (const float*)d_in[3];
    const float* W2 = (const float*)d_in[4];
    const float* b2 = (const float*)d_in[5];

    int N = in_sizes[0] / F0;
    int E = in_sizes[1] / 2;
    const int* row = ei;
    const int* col = ei + E;

    // workspace layout (4B words), Np = N padded to 64
    size_t Np = ((size_t)N + 63) & ~(size_t)63;
    int*   cnt     = (int*)d_ws;                 // Np (reused as cur)
    int*   ptr     = cnt + Np;                   // Np+64
    float* dinv    = (float*)(ptr + Np + 64);    // Np
    int*   partial = (int*)(dinv + Np);          // 1024
    uint2* edges   = (uint2*)(partial + 1024);   // E*2 words
    float* xw1     = (float*)(edges + E);        // N*64 (reused as h2w)
    float* out1    = xw1 + (size_t)N * F1;       // N*64
    int*   cur     = cnt;
    float* h2w     = xw1;
    float* out2    = (float*)d_out;

    int nbN  = (N + 255) / 256;          // scan segment count (phase A)
    int nbN1 = (N + 256) / 256;          // covers i == N tail (phase C)
    int nbE  = (E + 255) / 256;

    hipMemsetAsync(cnt, 0, (size_t)N * sizeof(int), stream);
    count_deg<<<nbE, 256, 0, stream>>>(col, cnt, E);
    scan_partial<<<nbN, 256, 0, stream>>>(cnt, partial, N);
    scan_block<<<1, 1024, 0, stream>>>(partial, nbN);
    scan_final<<<nbN1, 256, 0, stream>>>(cnt, partial, ptr, cur, dinv, N, E);
    edge_fill<<<nbE, 256, 0, stream>>>(row, col, dinv, cur, edges, E);

    gemm1<<<(N + 3) / 4, 256, 0, stream>>>(x, W1, xw1, N);
    agg1<<<(int)(((size_t)N * F1 + 255) / 256), 256, 0, stream>>>(ptr, edges, xw1, dinv, b1, out1, N);

    gemm2<<<(N + 7) / 8, 256, 0, stream>>>(out1, W2, h2w, N);
    agg2_lsm<<<(int)(((size_t)N * F2 + 255) / 256), 256, 0, stream>>>(ptr, edges, h2w, dinv, b2, out2, N);
}

// Round 5
// 216.196 us; speedup vs baseline: 1.8451x; 1.1500x over previous
//
#include <hip/hip_runtime.h>

#define F0 128
#define F1 64
#define F2 32

// ================= CSR build =================
__global__ void count_deg(const int* __restrict__ col, int* cnt, int E) {
    int e = blockIdx.x * 256 + threadIdx.x;
    if (e < E) atomicAdd(&cnt[col[e]], 1);
}

__global__ void scan_partial(const int* __restrict__ cnt, int* __restrict__ partial, int N) {
    __shared__ int red[256];
    int i = blockIdx.x * 256 + threadIdx.x;
    red[threadIdx.x] = (i < N) ? cnt[i] : 0;
    __syncthreads();
    for (int off = 128; off; off >>= 1) {
        if (threadIdx.x < off) red[threadIdx.x] += red[threadIdx.x + off];
        __syncthreads();
    }
    if (threadIdx.x == 0) partial[blockIdx.x] = red[0];
}

__global__ __launch_bounds__(1024) void scan_block(int* partial, int nb) {
    __shared__ int s[1024];
    int t = threadIdx.x;
    int v = (t < nb) ? partial[t] : 0;
    s[t] = v;
    __syncthreads();
    for (int off = 1; off < 1024; off <<= 1) {
        int u = (t >= off) ? s[t - off] : 0;
        __syncthreads();
        s[t] += u;
        __syncthreads();
    }
    if (t < nb) partial[t] = s[t] - v;
}

// cur may alias cnt: each element read once before any write.
__global__ void scan_final(const int* __restrict__ cnt, const int* __restrict__ partial,
                           int* __restrict__ ptr, int* __restrict__ cur,
                           float* __restrict__ dinv, int N, int E) {
    __shared__ int s[256];
    int t = threadIdx.x;
    int i = blockIdx.x * 256 + t;
    int v = (i < N) ? cnt[i] : 0;
    s[t] = v;
    __syncthreads();
    for (int off = 1; off < 256; off <<= 1) {
        int u = (t >= off) ? s[t - off] : 0;
        __syncthreads();
        s[t] += u;
        __syncthreads();
    }
    if (i < N) {
        int p = partial[blockIdx.x] + s[t] - v;
        ptr[i] = p;
        cur[i] = p;
        dinv[i] = rsqrtf((float)(v + 1));
    } else if (i == N) {
        ptr[N] = E;
    }
}

__global__ void edge_fill(const int* __restrict__ row, const int* __restrict__ col,
                          const float* __restrict__ dinv, int* cur,
                          uint2* __restrict__ edges, int E) {
    int e = blockIdx.x * 256 + threadIdx.x;
    if (e >= E) return;
    int r = row[e], c = col[e];
    float nrm = dinv[r] * dinv[c];
    int pos = atomicAdd(&cur[c], 1);
    edges[pos] = make_uint2((unsigned)r, __float_as_uint(nrm));
}

// ================= register-tiled GEMMs =================
__device__ __forceinline__ void fma4(float4& a, float xs, const float4& wv) {
    a.x = fmaf(xs, wv.x, a.x);
    a.y = fmaf(xs, wv.y, a.y);
    a.z = fmaf(xs, wv.z, a.z);
    a.w = fmaf(xs, wv.w, a.w);
}

// gemm1: xw = x @ W1, tile 64 rows x 64 cols, thread = 4x4 micro-tile.
// Xl rows XOR-swizzled at float4 granularity so the 4 per-thread row reads
// (stride 128 words -> same bank) spread across banks.
__global__ __launch_bounds__(256) void gemm1(const float* __restrict__ x,
                                             const float* __restrict__ W,
                                             float* __restrict__ xw, int N) {
    __shared__ float Xl[64 * F0];   // 32KB, swizzled
    __shared__ float Wl[F0 * F1];   // 32KB, linear [k][64]
    int tid = threadIdx.x;
    int base = blockIdx.x * 64;

    const float4* W4 = (const float4*)W;
    float4* Wl4 = (float4*)Wl;
#pragma unroll
    for (int i = 0; i < 8; ++i) Wl4[tid + 256 * i] = W4[tid + 256 * i];

    float4* Xl4 = (float4*)Xl;
#pragma unroll
    for (int i = 0; i < 8; ++i) {
        int idx = tid + 256 * i;          // 0..2047
        int r = idx >> 5, c4 = idx & 31;  // row, float4-group in row
        int gr = base + r;
        float4 v = (gr < N) ? ((const float4*)x)[(size_t)gr * 32 + c4]
                            : make_float4(0.f, 0.f, 0.f, 0.f);
        Xl4[r * 32 + (c4 ^ (r >> 2))] = v;   // swizzle: r>>2 in 0..15
    }
    __syncthreads();

    int tc = tid & 15, tr = tid >> 4;   // cols 4tc..+3, rows 4tr..+3
    float4 acc0 = make_float4(0.f, 0.f, 0.f, 0.f);
    float4 acc1 = acc0, acc2 = acc0, acc3 = acc0;
    const float4* Wl4c = (const float4*)Wl;
    const float4* Xl4c = (const float4*)Xl;

#pragma unroll 4
    for (int kk = 0; kk < 32; ++kk) {   // 4 k per iter
        float4 xv0 = Xl4c[(4 * tr + 0) * 32 + (kk ^ tr)];
        float4 xv1 = Xl4c[(4 * tr + 1) * 32 + (kk ^ tr)];
        float4 xv2 = Xl4c[(4 * tr + 2) * 32 + (kk ^ tr)];
        float4 xv3 = Xl4c[(4 * tr + 3) * 32 + (kk ^ tr)];
        float4 w0 = Wl4c[(4 * kk + 0) * 16 + tc];
        float4 w1 = Wl4c[(4 * kk + 1) * 16 + tc];
        float4 w2 = Wl4c[(4 * kk + 2) * 16 + tc];
        float4 w3 = Wl4c[(4 * kk + 3) * 16 + tc];
        fma4(acc0, xv0.x, w0); fma4(acc0, xv0.y, w1); fma4(acc0, xv0.z, w2); fma4(acc0, xv0.w, w3);
        fma4(acc1, xv1.x, w0); fma4(acc1, xv1.y, w1); fma4(acc1, xv1.z, w2); fma4(acc1, xv1.w, w3);
        fma4(acc2, xv2.x, w0); fma4(acc2, xv2.y, w1); fma4(acc2, xv2.z, w2); fma4(acc2, xv2.w, w3);
        fma4(acc3, xv3.x, w0); fma4(acc3, xv3.y, w1); fma4(acc3, xv3.z, w2); fma4(acc3, xv3.w, w3);
    }

    float4* xwo = (float4*)xw;
    int gr = base + 4 * tr;
    if (gr + 0 < N) xwo[(size_t)(gr + 0) * 16 + tc] = acc0;
    if (gr + 1 < N) xwo[(size_t)(gr + 1) * 16 + tc] = acc1;
    if (gr + 2 < N) xwo[(size_t)(gr + 2) * 16 + tc] = acc2;
    if (gr + 3 < N) xwo[(size_t)(gr + 3) * 16 + tc] = acc3;
}

// gemm2: hw = relu(h) @ W2, tile 128 rows x 32 cols, thread = 4x4 micro-tile.
__global__ __launch_bounds__(256) void gemm2(const float* __restrict__ h,
                                             const float* __restrict__ W,
                                             float* __restrict__ hw, int N) {
    __shared__ float Hl[128 * F1];  // 32KB, swizzled
    __shared__ float Wl[F1 * F2];   // 8KB, linear [k][32]
    int tid = threadIdx.x;
    int base = blockIdx.x * 128;

    const float4* W4 = (const float4*)W;
    float4* Wl4 = (float4*)Wl;
#pragma unroll
    for (int i = 0; i < 2; ++i) Wl4[tid + 256 * i] = W4[tid + 256 * i];

    float4* Hl4 = (float4*)Hl;
#pragma unroll
    for (int i = 0; i < 8; ++i) {
        int idx = tid + 256 * i;          // 0..2047
        int r = idx >> 4, c4 = idx & 15;  // row 0..127, float4-group 0..15
        int gr = base + r;
        float4 v = (gr < N) ? ((const float4*)h)[(size_t)gr * 16 + c4]
                            : make_float4(0.f, 0.f, 0.f, 0.f);
        v.x = fmaxf(v.x, 0.f); v.y = fmaxf(v.y, 0.f);
        v.z = fmaxf(v.z, 0.f); v.w = fmaxf(v.w, 0.f);
        Hl4[r * 16 + (c4 ^ ((r >> 2) & 15))] = v;
    }
    __syncthreads();

    int tc = tid & 7, tr = tid >> 3;    // cols 4tc..+3, rows 4tr..+3 (tr 0..31)
    float4 acc0 = make_float4(0.f, 0.f, 0.f, 0.f);
    float4 acc1 = acc0, acc2 = acc0, acc3 = acc0;
    const float4* Wl4c = (const float4*)Wl;
    const float4* Hl4c = (const float4*)Hl;

#pragma unroll 4
    for (int kk = 0; kk < 16; ++kk) {   // 4 k per iter
        int sw = kk ^ (tr & 15);
        float4 xv0 = Hl4c[(4 * tr + 0) * 16 + sw];
        float4 xv1 = Hl4c[(4 * tr + 1) * 16 + sw];
        float4 xv2 = Hl4c[(4 * tr + 2) * 16 + sw];
        float4 xv3 = Hl4c[(4 * tr + 3) * 16 + sw];
        float4 w0 = Wl4c[(4 * kk + 0) * 8 + tc];
        float4 w1 = Wl4c[(4 * kk + 1) * 8 + tc];
        float4 w2 = Wl4c[(4 * kk + 2) * 8 + tc];
        float4 w3 = Wl4c[(4 * kk + 3) * 8 + tc];
        fma4(acc0, xv0.x, w0); fma4(acc0, xv0.y, w1); fma4(acc0, xv0.z, w2); fma4(acc0, xv0.w, w3);
        fma4(acc1, xv1.x, w0); fma4(acc1, xv1.y, w1); fma4(acc1, xv1.z, w2); fma4(acc1, xv1.w, w3);
        fma4(acc2, xv2.x, w0); fma4(acc2, xv2.y, w1); fma4(acc2, xv2.z, w2); fma4(acc2, xv2.w, w3);
        fma4(acc3, xv3.x, w0); fma4(acc3, xv3.y, w1); fma4(acc3, xv3.z, w2); fma4(acc3, xv3.w, w3);
    }

    float4* hwo = (float4*)hw;
    int gr = base + 4 * tr;
    if (gr + 0 < N) hwo[(size_t)(gr + 0) * 8 + tc] = acc0;
    if (gr + 1 < N) hwo[(size_t)(gr + 1) * 8 + tc] = acc1;
    if (gr + 2 < N) hwo[(size_t)(gr + 2) * 8 + tc] = acc2;
    if (gr + 3 < N) hwo[(size_t)(gr + 3) * 8 + tc] = acc3;
}

// ================= layer 1 aggregation (gather): one wave per node =================
__global__ void agg1(const int* __restrict__ ptr, const uint2* __restrict__ edges,
                     const float* __restrict__ xw, const float* __restrict__ dinv,
                     const float* __restrict__ b, float* __restrict__ out, int N) {
    int t = blockIdx.x * 256 + threadIdx.x;
    int i = t >> 6, j = t & 63;
    if (i >= N) return;
    float d = dinv[i];
    float acc = xw[(size_t)i * F1 + j] * d * d + b[j];
    int e = ptr[i], end = ptr[i + 1];
    for (; e + 1 < end; e += 2) {
        uint2 e0 = edges[e], e1 = edges[e + 1];
        float v0 = xw[(size_t)e0.x * F1 + j];
        float v1 = xw[(size_t)e1.x * F1 + j];
        acc += v0 * __uint_as_float(e0.y);
        acc += v1 * __uint_as_float(e1.y);
    }
    if (e < end) {
        uint2 e0 = edges[e];
        acc += xw[(size_t)e0.x * F1 + j] * __uint_as_float(e0.y);
    }
    out[(size_t)i * F1 + j] = acc;
}

// ================= layer 2 aggregation + fused log_softmax =================
__global__ void agg2_lsm(const int* __restrict__ ptr, const uint2* __restrict__ edges,
                         const float* __restrict__ hw, const float* __restrict__ dinv,
                         const float* __restrict__ b, float* __restrict__ out, int N) {
    int t = blockIdx.x * 256 + threadIdx.x;
    int i = t >> 5, j = t & 31;
    if (i >= N) return;
    float d = dinv[i];
    float acc = hw[(size_t)i * F2 + j] * d * d + b[j];
    int e = ptr[i], end = ptr[i + 1];
    for (; e + 1 < end; e += 2) {
        uint2 e0 = edges[e], e1 = edges[e + 1];
        float v0 = hw[(size_t)e0.x * F2 + j];
        float v1 = hw[(size_t)e1.x * F2 + j];
        acc += v0 * __uint_as_float(e0.y);
        acc += v1 * __uint_as_float(e1.y);
    }
    if (e < end) {
        uint2 e0 = edges[e];
        acc += hw[(size_t)e0.x * F2 + j] * __uint_as_float(e0.y);
    }
    float m = acc;
    for (int off = 16; off; off >>= 1) m = fmaxf(m, __shfl_xor(m, off, 32));
    float s = expf(acc - m);
    for (int off = 16; off; off >>= 1) s += __shfl_xor(s, off, 32);
    out[(size_t)i * F2 + j] = acc - m - logf(s);
}

extern "C" void kernel_launch(void* const* d_in, const int* in_sizes, int n_in,
                              void* d_out, int out_size, void* d_ws, size_t ws_size,
                              hipStream_t stream) {
    const float* x  = (const float*)d_in[0];
    const int*   ei = (const int*)d_in[1];
    const float* W1 = (const float*)d_in[2];
    const float* b1 = (const float*)d_in[3];
    const float* W2 = (const float*)d_in[4];
    const float* b2 = (const float*)d_in[5];

    int N = in_sizes[0] / F0;
    int E = in_sizes[1] / 2;
    const int* row = ei;
    const int* col = ei + E;

    size_t Np = ((size_t)N + 63) & ~(size_t)63;
    int*   cnt     = (int*)d_ws;
    int*   ptr     = cnt + Np;
    float* dinv    = (float*)(ptr + Np + 64);
    int*   partial = (int*)(dinv + Np);
    uint2* edges   = (uint2*)(partial + 1024);
    float* xw1     = (float*)(edges + E);
    float* out1    = xw1 + (size_t)N * F1;
    int*   cur     = cnt;
    float* h2w     = xw1;
    float* out2    = (float*)d_out;

    int nbN  = (N + 255) / 256;
    int nbN1 = (N + 256) / 256;
    int nbE  = (E + 255) / 256;

    hipMemsetAsync(cnt, 0, (size_t)N * sizeof(int), stream);
    count_deg<<<nbE, 256, 0, stream>>>(col, cnt, E);
    scan_partial<<<nbN, 256, 0, stream>>>(cnt, partial, N);
    scan_block<<<1, 1024, 0, stream>>>(partial, nbN);
    scan_final<<<nbN1, 256, 0, stream>>>(cnt, partial, ptr, cur, dinv, N, E);
    edge_fill<<<nbE, 256, 0, stream>>>(row, col, dinv, cur, edges, E);

    gemm1<<<(N + 63) / 64, 256, 0, stream>>>(x, W1, xw1, N);
    agg1<<<(int)(((size_t)N * F1 + 255) / 256), 256, 0, stream>>>(ptr, edges, xw1, dinv, b1, out1, N);

    gemm2<<<(N + 127) / 128, 256, 0, stream>>>(out1, W2, h2w, N);
    agg2_lsm<<<(int)(((size_t)N * F2 + 255) / 256), 256, 0, stream>>>(ptr, edges, h2w, dinv, b2, out2, N);
}